// Round 1
// baseline (2228.381 us; speedup 1.0000x reference)
//
#include <hip/hip_runtime.h>

// ---------------------------------------------------------------------------
// 4-layer GRU stack (Keras reset_after), B=128, T=384, U=D=256.
//
// Redesign: the serial h-recurrence for each (layer, 16-row chunk) lives in
// ONE 512-thread block (8 waves) -> h exchange via LDS, not MALL.
//   rec block (32):  per step  acc = h(t-1) @ R  (M=16,N=768,K=256, 384 MFMA)
//                    + gates fully in-wave (each wave owns z,r,h for 32 units)
//                    + h(t) written back into LDS A-fragments for step t+1.
//   proj blocks (64, 2 per (l,c) by t-parity): xp(t) = x_l(t) @ W + biases,
//                    pipelined one step ahead, off the critical path.
// Cross-block traffic: h-ring (epoch-tagged ulls, self-validating) and
// xp-ring (flag release: stores drained by __syncthreads' vmcnt(0), then
// flag store). All flags prefetched one step ahead -> steady-state step has
// no blocking memory waits.
// Weights: 6 B-fragment tiles per wave (5 in VGPRs=160, 1 in LDS), same
// repacked Wp as before: kt 0..7 = input half (proj), kt 8..15 = recurrent
// half (rec).
// ---------------------------------------------------------------------------

#define LAYERS 4
#define TSTEPS 384
#define WPL (48 * 16 * 64 * 8)     // repacked weight elems per layer
#define TILE_STRIDE (16 * 64 * 8)  // 8192 elems per 16-col tile
#define RING_H 16
#define RING_X 8
#define HSLOT 2048ull              // ulls per h slot (16 rows x 128 words)
#define HGRP (RING_H * HSLOT)      // ulls per (l,c) h group
#define XSLOT_B 32768ull           // 16KB zr (f16) + 16KB ip (f32)
#define XGRP_B (RING_X * XSLOT_B)

typedef _Float16 half8 __attribute__((ext_vector_type(8)));
typedef float    f32x4 __attribute__((ext_vector_type(4)));
typedef unsigned long long ull;

#define WP_OFF   0
#define BP_OFF   (LAYERS * WPL * 2)                 // 3,145,728
#define FLAG_OFF (BP_OFF + LAYERS * 1024 * 4)       // +16 KB
#define FLAG_BYTES 4096
#define EP_OFF   (FLAG_OFF + FLAG_BYTES)            // epoch counter (NOT memset)
#define HBUF_OFF (4ull << 20)
#define XP_OFF   (HBUF_OFF + 24ull * HGRP * 8ull)   // 4M + 6M = 10,485,760

#define AL __ATOMIC_RELAXED
#define SS __HIP_MEMORY_SCOPE_SYSTEM
#define MFMA __builtin_amdgcn_mfma_f32_16x16x32_f16

// ---------------------------------------------------------------------------
// Repack (unchanged layout): W[l] -> [tile=48][kt=16][lane=64][8] fp16 B-frags.
// n = tile*16 + (lane&15), k = kt*32 + (lane>>4)*8 + j; k<256 input, >=256 rec.
// Bias: [0:512]=b_in+b_rec (z,r), [512:768]=b_in_h, [768:1024]=b_rec_h.
// Also bumps the launch epoch (distinguishes ring tags across launches).
// ---------------------------------------------------------------------------
__global__ void repack_kernel(const float* __restrict__ k0, const float* __restrict__ rk0,
                              const float* __restrict__ b0, const float* __restrict__ kern,
                              const float* __restrict__ rkern, const float* __restrict__ bias,
                              _Float16* __restrict__ Wp, float* __restrict__ Bp,
                              unsigned* __restrict__ ep)
{
    int idx = blockIdx.x * 256 + threadIdx.x;
    if (idx == 0) ep[0] = ep[0] + 1u;
    const int total_w = LAYERS * WPL;
    if (idx < total_w) {
        int l = idx / WPL;
        int r = idx - l * WPL;
        int j    = r & 7;
        int lane = (r >> 3) & 63;
        int kt   = (r >> 9) & 15;
        int tile = r >> 13;
        int n = tile * 16 + (lane & 15);
        int k = kt * 32 + (lane >> 4) * 8 + j;
        float v;
        if (l == 0) {
            v = (k < 256) ? k0[(size_t)k * 768 + n] : rk0[(size_t)(k - 256) * 768 + n];
        } else {
            const float* kk = kern  + (size_t)(l - 1) * 256 * 768;
            const float* rk = rkern + (size_t)(l - 1) * 256 * 768;
            v = (k < 256) ? kk[(size_t)k * 768 + n] : rk[(size_t)(k - 256) * 768 + n];
        }
        Wp[idx] = (_Float16)v;
    } else {
        int ib = idx - total_w;
        if (ib < LAYERS * 1024) {
            int l = ib >> 10;
            int i = ib & 1023;
            const float* bs = (l == 0) ? b0 : (bias + (size_t)(l - 1) * 2 * 768);
            float v;
            if (i < 512)      v = bs[i] + bs[768 + i];
            else if (i < 768) v = bs[512 + (i - 512)];
            else              v = bs[768 + 512 + (i - 768)];
            Bp[l * 1024 + i] = v;
        }
    }
}

// ---------------------------------------------------------------------------
// Persistent kernel: blocks 0..31 = rec (l=bi>>3, c=bi&7);
//                    blocks 32..95 = proj (l=p>>4, c=(p>>1)&7, parity=p&1).
// 512 threads = 8 waves; wave w owns units 32w..32w+31 (tiles z,r,h pairs).
// ---------------------------------------------------------------------------
__launch_bounds__(512, 2)
__global__ void gru_kernel(const float* __restrict__ x,
                           const _Float16* __restrict__ Wp,
                           const float* __restrict__ Bp,
                           ull* __restrict__ hbuf,
                           unsigned* __restrict__ flags,
                           const unsigned* __restrict__ ep,
                           char* __restrict__ xpb,
                           float* __restrict__ out)
{
    // A-fragments in MFMA order: Af[buf][kt][lane(+pad)][8]; pad row 65 breaks
    // bank alignment of the staging writes; a-frag reads stay lane-contiguous.
    __shared__ _Float16 Af[2][8][65][8];   // 16.25 KB
    __shared__ _Float16 Bl[8][8][64][8];   // 64 KB: 6th B-tile per wave

    const int tid  = threadIdx.x;
    const int lane = tid & 63;
    const int w    = tid >> 6;
    const int lo16 = lane & 15;
    const int q    = lane >> 4;
    const unsigned tagbase = ep[0] * 1024u;

    const bool isrec = (blockIdx.x < 32);
    int l, c, par = 0;
    if (isrec) { l = blockIdx.x >> 3; c = blockIdx.x & 7; }
    else { int p = blockIdx.x - 32; l = p >> 4; c = (p >> 1) & 7; par = p & 1; }
    const int b0row = c * 16;

    // ---- weight tiles: wave w -> units 32w..32w+31, gates z,r,h ----
    half8 bf0[8], bf1[8], bf2[8], bf3[8], bf4[8];
    {
        const _Float16* wb = Wp + (size_t)l * WPL;
        const int kb = isrec ? 8 : 0;   // rec: recurrent half; proj: input half
        const int t0 = 2*w, t1 = 2*w+1, t2 = 16+2*w, t3 = 17+2*w, t4 = 32+2*w, t5 = 33+2*w;
#pragma unroll
        for (int kt = 0; kt < 8; ++kt) {
            size_t o = (size_t)((kb + kt) * 64 + lane) * 8;
            bf0[kt] = *(const half8*)(wb + (size_t)t0 * TILE_STRIDE + o);
            bf1[kt] = *(const half8*)(wb + (size_t)t1 * TILE_STRIDE + o);
            bf2[kt] = *(const half8*)(wb + (size_t)t2 * TILE_STRIDE + o);
            bf3[kt] = *(const half8*)(wb + (size_t)t3 * TILE_STRIDE + o);
            bf4[kt] = *(const half8*)(wb + (size_t)t4 * TILE_STRIDE + o);
            *(half8*)&Bl[w][kt][lane][0] = *(const half8*)(wb + (size_t)t5 * TILE_STRIDE + o);
        }
    }

    if (isrec) {
        // =================== RECURRENCE BLOCK ===================
        ull* hb_own = hbuf + (size_t)(l * 8 + c) * HGRP;              // l<3 only
        char* xg = xpb + (size_t)(l * 8 + c) * XGRP_B;
        unsigned* rprog = flags + 128 + (l * 8 + c);
        const ull* xf_pair = (const ull*)(flags + (l * 8 + c) * 2);
        const ull* pp_pair = (const ull*)(flags + ((l < 3 ? l + 1 : l) * 8 + c) * 2);

        float bh0, bh1;   // b_rec_h for this lane's two units
        {
            const float* bp = Bp + l * 1024;
            bh0 = bp[768 + 32 * w + lo16];
            bh1 = bp[768 + 32 * w + 16 + lo16];
        }

        // h(-1) = 0
        if (tid < 520) {
            half8 z8 = {};
            *(half8*)&Af[0][tid / 65][tid % 65][0] = z8;
        }

        float hprev[2][4] = {{0,0,0,0},{0,0,0,0}};
        ull xzr[4], xip[4];
        ull xfv, ppv = 0;

        // prologue: wait for xp(0) (parity-0 flag >= 1), then prefetch it
        xfv = __hip_atomic_load(xf_pair, AL, SS);
        while ((unsigned)(xfv & 0xffffffffu) < 1u) {
            __builtin_amdgcn_s_sleep(1);
            xfv = __hip_atomic_load(xf_pair, AL, SS);
        }
        {
            const ull* xz = (const ull*)xg;
            const ull* xi = (const ull*)(xg + 16384);
#pragma unroll
            for (int g = 0; g < 4; ++g)
                xzr[g] = __hip_atomic_load(xz + (w * 4 + g) * 64 + lane, AL, SS);
#pragma unroll
            for (int gi = 0; gi < 2; ++gi)
#pragma unroll
                for (int h2 = 0; h2 < 2; ++h2)
                    xip[gi * 2 + h2] = __hip_atomic_load(xi + ((w * 2 + gi) * 64 + lane) * 2 + h2, AL, SS);
        }
        xfv = __hip_atomic_load(xf_pair, AL, SS);
        if (l < 3) ppv = __hip_atomic_load(pp_pair, AL, SS);
        __syncthreads();

        for (int t = 0; t < TSTEPS; ++t) {
            const int cb = t & 1, nb = cb ^ 1;

            // ---- acc init: z,r from xp (all biases folded); h from b_rec_h ----
            f32x4 acc0, acc1, acc2, acc3, acc4, acc5;
            {
                union { ull u; _Float16 h[4]; } v0, v1, v2, v3;
                v0.u = xzr[0]; v1.u = xzr[1]; v2.u = xzr[2]; v3.u = xzr[3];
                acc0 = (f32x4){(float)v0.h[0], (float)v0.h[1], (float)v0.h[2], (float)v0.h[3]};
                acc1 = (f32x4){(float)v1.h[0], (float)v1.h[1], (float)v1.h[2], (float)v1.h[3]};
                acc2 = (f32x4){(float)v2.h[0], (float)v2.h[1], (float)v2.h[2], (float)v2.h[3]};
                acc3 = (f32x4){(float)v3.h[0], (float)v3.h[1], (float)v3.h[2], (float)v3.h[3]};
            }
            acc4 = (f32x4){bh0, bh0, bh0, bh0};
            acc5 = (f32x4){bh1, bh1, bh1, bh1};

            // ---- h(t-1) @ R : 48 MFMAs/wave, a-frags wave-contiguous ----
#pragma unroll
            for (int kt = 0; kt < 8; ++kt) {
                half8 a  = *(const half8*)&Af[cb][kt][lane][0];
                half8 bl = *(const half8*)&Bl[w][kt][lane][0];
                acc0 = MFMA(a, bf0[kt], acc0, 0, 0, 0);
                acc1 = MFMA(a, bf1[kt], acc1, 0, 0, 0);
                acc2 = MFMA(a, bf2[kt], acc2, 0, 0, 0);
                acc3 = MFMA(a, bf3[kt], acc3, 0, 0, 0);
                acc4 = MFMA(a, bf4[kt], acc4, 0, 0, 0);
                acc5 = MFMA(a, bl,      acc5, 0, 0, 0);
            }

            // ---- gates, fully in-wave (lane: 2 units x 4 rows) ----
            float hn[2][4];
            {
                union { ull u; float f[2]; } i0, i1, i2, i3;
                i0.u = xip[0]; i1.u = xip[1]; i2.u = xip[2]; i3.u = xip[3];
                const float ipv[2][4] = {{i0.f[0], i0.f[1], i1.f[0], i1.f[1]},
                                         {i2.f[0], i2.f[1], i3.f[0], i3.f[1]}};
#pragma unroll
                for (int uu = 0; uu < 2; ++uu) {
#pragma unroll
                    for (int j = 0; j < 4; ++j) {
                        float zp = uu ? acc1[j] : acc0[j];
                        float rp = uu ? acc3[j] : acc2[j];
                        float hp = uu ? acc5[j] : acc4[j];
                        float z  = 1.f / (1.f + __expf(-zp));
                        float r  = 1.f / (1.f + __expf(-rp));
                        float pre = ipv[uu][j] + r * hp;
                        float e  = __expf(2.f * pre);
                        float th = 1.f - 2.f / (e + 1.f);
                        float h  = z * hprev[uu][j] + (1.f - z) * th;
                        hprev[uu][j] = h;
                        hn[uu][j] = h;
                    }
                }
            }

            // ---- h(t) -> Af[nb] fragment order (unit u is the k index) ----
#pragma unroll
            for (int uu = 0; uu < 2; ++uu) {
                const int lg = 2 * uu + (lo16 >> 3);
                const int j7 = lo16 & 7;
#pragma unroll
                for (int j = 0; j < 4; ++j)
                    Af[nb][w][lg * 16 + q * 4 + j][j7] = (_Float16)hn[uu][j];
            }
            if (l == 3 && t == TSTEPS - 1) {
#pragma unroll
                for (int uu = 0; uu < 2; ++uu)
#pragma unroll
                    for (int j = 0; j < 4; ++j)
                        out[(size_t)(b0row + q * 4 + j) * 256 + 32 * w + uu * 16 + lo16] = hn[uu][j];
            }
            __syncthreads();   // Af[nb] complete; Af[cb] reads done

            // ---- off-critical-path: prefetch xp(t+1), publish h(t), flags ----
            if (t + 1 < TSTEPS) {
                const unsigned need = (unsigned)(t + 2);
                unsigned fv = (unsigned)(((t + 1) & 1) ? (xfv >> 32) : (xfv & 0xffffffffu));
                while (fv < need) {                       // rare: proj leads by ring slack
                    __builtin_amdgcn_s_sleep(1);
                    xfv = __hip_atomic_load(xf_pair, AL, SS);
                    fv = (unsigned)(((t + 1) & 1) ? (xfv >> 32) : (xfv & 0xffffffffu));
                }
                const char* xs = xg + (size_t)((t + 1) & (RING_X - 1)) * XSLOT_B;
                const ull* xz = (const ull*)xs;
                const ull* xi = (const ull*)(xs + 16384);
#pragma unroll
                for (int g = 0; g < 4; ++g)
                    xzr[g] = __hip_atomic_load(xz + (w * 4 + g) * 64 + lane, AL, SS);
#pragma unroll
                for (int gi = 0; gi < 2; ++gi)
#pragma unroll
                    for (int h2 = 0; h2 < 2; ++h2)
                        xip[gi * 2 + h2] = __hip_atomic_load(xi + ((w * 2 + gi) * 64 + lane) * 2 + h2, AL, SS);
            }
            if (l < 3) {
                if (t >= RING_H) {                        // ring backpressure (prefetched)
                    const unsigned need = (unsigned)(t - RING_H + 1);
                    unsigned p0 = (unsigned)(ppv & 0xffffffffu), p1 = (unsigned)(ppv >> 32);
                    while (p0 < need || p1 < need) {
                        __builtin_amdgcn_s_sleep(1);
                        ppv = __hip_atomic_load(pp_pair, AL, SS);
                        p0 = (unsigned)(ppv & 0xffffffffu); p1 = (unsigned)(ppv >> 32);
                    }
                }
                const int row = tid >> 5, wq = tid & 31;
                ull* dst = hb_own + (size_t)(t & (RING_H - 1)) * HSLOT + row * 128 + wq * 4;
                const ull tg = ((ull)(tagbase + (unsigned)(t + 1))) << 32;
#pragma unroll
                for (int m = 0; m < 4; ++m) {
                    const int wi = wq * 4 + m;            // word wi <-> units 2wi,2wi+1
                    const unsigned v = *(const unsigned*)&Af[nb][wi >> 4][((wi >> 2) & 3) * 16 + row][(wi & 3) * 2];
                    __hip_atomic_store(dst + m, tg | (ull)v, AL, SS);
                }
                ppv = __hip_atomic_load(pp_pair, AL, SS); // refresh for next step
            }
            if (t + 1 < TSTEPS) xfv = __hip_atomic_load(xf_pair, AL, SS);
            if (tid == 0) __hip_atomic_store(rprog, (unsigned)(t + 1), AL, SS);
        }
    } else {
        // =================== PROJECTION BLOCK (parity par) ===================
        const ull* hb_up = hbuf + (size_t)((l > 0 ? l - 1 : 0) * 8 + c) * HGRP;
        char* xg = xpb + (size_t)(l * 8 + c) * XGRP_B;
        unsigned* my_flag = flags + (l * 8 + c) * 2 + par;
        unsigned* rprog = flags + 128 + (l * 8 + c);
        float bz0, bz1, br0, br1, bi0, bi1;
        {
            const float* bp = Bp + l * 1024;
            const int u0 = 32 * w + lo16, u1 = u0 + 16;
            bz0 = bp[u0];       bz1 = bp[u1];
            br0 = bp[256 + u0]; br1 = bp[256 + u1];
            bi0 = bp[512 + u0]; bi1 = bp[512 + u1];
        }
        unsigned rpv = 0;
        const int row = tid >> 5, g16x = tid & 31;

        for (int t = par; t < TSTEPS; t += 2) {
            // ---- stage A(t): x (l==0) or tagged h-ring (l>0) -> Af[0] frags ----
            if (l == 0) {
                const float* sp = x + ((size_t)(b0row + row) * TSTEPS + t) * 256 + g16x * 8;
                f32x4 a0 = *(const f32x4*)sp;
                f32x4 a1 = *(const f32x4*)(sp + 4);
                half8 hh;
                hh[0] = (_Float16)a0[0]; hh[1] = (_Float16)a0[1];
                hh[2] = (_Float16)a0[2]; hh[3] = (_Float16)a0[3];
                hh[4] = (_Float16)a1[0]; hh[5] = (_Float16)a1[1];
                hh[6] = (_Float16)a1[2]; hh[7] = (_Float16)a1[3];
                *(half8*)&Af[0][g16x >> 2][(g16x & 3) * 16 + row][0] = hh;
            } else {
                const ull* spx = hb_up + (size_t)(t & (RING_H - 1)) * HSLOT + row * 128 + g16x * 4;
                const unsigned tg = tagbase + (unsigned)(t + 1);
                ull v0 = __hip_atomic_load(spx + 0, AL, SS);
                ull v1 = __hip_atomic_load(spx + 1, AL, SS);
                ull v2 = __hip_atomic_load(spx + 2, AL, SS);
                ull v3 = __hip_atomic_load(spx + 3, AL, SS);
                for (;;) {
                    bool ok = true;
                    if ((unsigned)(v0 >> 32) != tg) { v0 = __hip_atomic_load(spx + 0, AL, SS); ok = false; }
                    if ((unsigned)(v1 >> 32) != tg) { v1 = __hip_atomic_load(spx + 1, AL, SS); ok = false; }
                    if ((unsigned)(v2 >> 32) != tg) { v2 = __hip_atomic_load(spx + 2, AL, SS); ok = false; }
                    if ((unsigned)(v3 >> 32) != tg) { v3 = __hip_atomic_load(spx + 3, AL, SS); ok = false; }
                    if (ok) break;
                    __builtin_amdgcn_s_sleep(1);
                }
                union { unsigned u[4]; half8 h; } pk;
                pk.u[0] = (unsigned)v0; pk.u[1] = (unsigned)v1;
                pk.u[2] = (unsigned)v2; pk.u[3] = (unsigned)v3;
                *(half8*)&Af[0][g16x >> 2][(g16x & 3) * 16 + row][0] = pk.h;
            }
            __syncthreads();

            // ---- xp = A @ Wk + bias (acc-initialized) ----
            f32x4 acc0 = {bz0, bz0, bz0, bz0}, acc1 = {bz1, bz1, bz1, bz1};
            f32x4 acc2 = {br0, br0, br0, br0}, acc3 = {br1, br1, br1, br1};
            f32x4 acc4 = {bi0, bi0, bi0, bi0}, acc5 = {bi1, bi1, bi1, bi1};
#pragma unroll
            for (int kt = 0; kt < 8; ++kt) {
                half8 a  = *(const half8*)&Af[0][kt][lane][0];
                half8 bl = *(const half8*)&Bl[w][kt][lane][0];
                acc0 = MFMA(a, bf0[kt], acc0, 0, 0, 0);
                acc1 = MFMA(a, bf1[kt], acc1, 0, 0, 0);
                acc2 = MFMA(a, bf2[kt], acc2, 0, 0, 0);
                acc3 = MFMA(a, bf3[kt], acc3, 0, 0, 0);
                acc4 = MFMA(a, bf4[kt], acc4, 0, 0, 0);
                acc5 = MFMA(a, bl,      acc5, 0, 0, 0);
            }
            __syncthreads();   // A consumed: next stage may overwrite Af[0]

            // ---- xp-ring backpressure vs rec consumption ----
            if (t >= RING_X) {
                const unsigned need = (unsigned)(t - RING_X + 1);
                while (rpv < need) {
                    __builtin_amdgcn_s_sleep(1);
                    rpv = __hip_atomic_load(rprog, AL, SS);
                }
            }

            // ---- pack + store xp(t): z,r as f16, ip (h input part) as f32 ----
            {
                char* xs = xg + (size_t)(t & (RING_X - 1)) * XSLOT_B;
                ull* xz = (ull*)xs;
                ull* xi = (ull*)(xs + 16384);
                union { ull u; _Float16 h[4]; } pz;
                pz.h[0] = (_Float16)acc0[0]; pz.h[1] = (_Float16)acc0[1];
                pz.h[2] = (_Float16)acc0[2]; pz.h[3] = (_Float16)acc0[3];
                __hip_atomic_store(xz + (w * 4 + 0) * 64 + lane, pz.u, AL, SS);
                pz.h[0] = (_Float16)acc1[0]; pz.h[1] = (_Float16)acc1[1];
                pz.h[2] = (_Float16)acc1[2]; pz.h[3] = (_Float16)acc1[3];
                __hip_atomic_store(xz + (w * 4 + 1) * 64 + lane, pz.u, AL, SS);
                pz.h[0] = (_Float16)acc2[0]; pz.h[1] = (_Float16)acc2[1];
                pz.h[2] = (_Float16)acc2[2]; pz.h[3] = (_Float16)acc2[3];
                __hip_atomic_store(xz + (w * 4 + 2) * 64 + lane, pz.u, AL, SS);
                pz.h[0] = (_Float16)acc3[0]; pz.h[1] = (_Float16)acc3[1];
                pz.h[2] = (_Float16)acc3[2]; pz.h[3] = (_Float16)acc3[3];
                __hip_atomic_store(xz + (w * 4 + 3) * 64 + lane, pz.u, AL, SS);
                union { ull u; float f[2]; } pi;
                pi.f[0] = acc4[0]; pi.f[1] = acc4[1];
                __hip_atomic_store(xi + ((w * 2 + 0) * 64 + lane) * 2 + 0, pi.u, AL, SS);
                pi.f[0] = acc4[2]; pi.f[1] = acc4[3];
                __hip_atomic_store(xi + ((w * 2 + 0) * 64 + lane) * 2 + 1, pi.u, AL, SS);
                pi.f[0] = acc5[0]; pi.f[1] = acc5[1];
                __hip_atomic_store(xi + ((w * 2 + 1) * 64 + lane) * 2 + 0, pi.u, AL, SS);
                pi.f[0] = acc5[2]; pi.f[1] = acc5[3];
                __hip_atomic_store(xi + ((w * 2 + 1) * 64 + lane) * 2 + 1, pi.u, AL, SS);
            }
            // __syncthreads drains each wave's stores (vmcnt(0) before s_barrier)
            // -> after it, ALL waves' xp stores are globally visible; then flag.
            __syncthreads();
            if (tid == 0) __hip_atomic_store(my_flag, (unsigned)(t + 1), AL, SS);
            rpv = __hip_atomic_load(rprog, AL, SS);   // refresh for next own-step
        }
    }
}

extern "C" void kernel_launch(void* const* d_in, const int* in_sizes, int n_in,
                              void* d_out, int out_size, void* d_ws, size_t ws_size,
                              hipStream_t stream)
{
    const float* x     = (const float*)d_in[0];
    const float* k0    = (const float*)d_in[1];
    const float* rk0   = (const float*)d_in[2];
    const float* b0    = (const float*)d_in[3];
    const float* kern  = (const float*)d_in[4];
    const float* rkern = (const float*)d_in[5];
    const float* bias  = (const float*)d_in[6];
    float* out = (float*)d_out;

    char* ws = (char*)d_ws;
    _Float16*  Wp    = (_Float16*)(ws + WP_OFF);
    float*     Bp    = (float*)(ws + BP_OFF);
    unsigned*  flags = (unsigned*)(ws + FLAG_OFF);
    unsigned*  ep    = (unsigned*)(ws + EP_OFF);
    ull*       hbuf  = (ull*)(ws + HBUF_OFF);
    char*      xpb   = ws + XP_OFF;

    hipMemsetAsync(flags, 0, FLAG_BYTES, stream);

    const int total = LAYERS * WPL + LAYERS * 1024;
    repack_kernel<<<(total + 255) / 256, 256, 0, stream>>>(k0, rk0, b0, kern, rkern, bias, Wp, Bp, ep);

    gru_kernel<<<96, 512, 0, stream>>>(x, Wp, Bp, hbuf, flags, ep, xpb, out);
}

// Round 3
// 1660.140 us; speedup vs baseline: 1.3423x; 1.3423x over previous
//
#include <hip/hip_runtime.h>
#include <hip/hip_fp16.h>

// ---------------------------------------------------------------------------
// 4-layer GRU stack (Keras reset_after), B=128, T=384, U=D=256.
// 256 persistent blocks = 4 layers x 8 chunks(16 rows) x 8 unit-slices(32 u).
// Weight B-fragments in REGISTERS (64 VGPRs/wave). Per step: M=16,N=96,K=512.
// A is stored in LDS in MFMA FRAGMENT ORDER (Af[kt][lane][8]) so the a-frag
// read is a wave-contiguous ds_read_b128 (conflict-free).
// Cross-block h exchange: epoch-tagged 8-byte words ({epoch|h1|h0}) in a
// 16-deep MALL ring, relaxed AGENT-scope atomics; consumers spin on the
// DATA tags (self-validating — no flag/data ordering assumptions).
//
// R3 change (single variable vs the proven 1652us R0 kernel):
//   __HIP_MEMORY_SCOPE_SYSTEM -> __HIP_MEMORY_SCOPE_AGENT on ALL ring/flag
//   atomics. System scope = host-coherent fine-grained = uncached HBM round
//   trips (counters: 1.4GB HBM traffic = entire ring payload). Agent scope
//   is sufficient for GPU-only cross-XCD communication and is served at the
//   MALL (Infinity Cache) -> ~2x lower hop latency, no HBM transactions.
// ---------------------------------------------------------------------------

#define LAYERS 4
#define TSTEPS 384
#define NCH    8
#define WPL    (48 * 16 * 64 * 8)  // repacked weight elems per layer
#define TILE_STRIDE (16 * 64 * 8)  // 8192 elems per 16-col tile
#define RING   16
#define SLOT_ULL (16 * 128)        // 16 rows x 128 tagged ulls per slot
#define GRP_ULL  (RING * SLOT_ULL)

typedef _Float16 half8 __attribute__((ext_vector_type(8)));
typedef float    f32x4 __attribute__((ext_vector_type(4)));
typedef unsigned uint4v __attribute__((ext_vector_type(4)));
typedef unsigned long long ull;

// ws layout (bytes)
#define WP_OFF   0
#define BP_OFF   (LAYERS * WPL * 2)                 // 3,145,728
#define FLAG_OFF (BP_OFF + LAYERS * 1024 * 4)       // +16 KB
#define FLAG_BYTES 4096
#define HBUF_OFF (4 * 1024 * 1024)

#define SCOPE __HIP_MEMORY_SCOPE_AGENT

// ---------------------------------------------------------------------------
// Repack: W[l] -> [tile=48][kt=16][lane=64][8] fp16 B-fragments.
// n = tile*16 + (lane&15), k = kt*32 + (lane>>4)*8 + j.
// Bias: [0:512]=b_in+b_rec (z,r), [512:768]=b_in_h, [768:1024]=b_rec_h.
// ---------------------------------------------------------------------------
__global__ void repack_kernel(const float* __restrict__ k0, const float* __restrict__ rk0,
                              const float* __restrict__ b0, const float* __restrict__ kern,
                              const float* __restrict__ rkern, const float* __restrict__ bias,
                              _Float16* __restrict__ Wp, float* __restrict__ Bp)
{
    int idx = blockIdx.x * 256 + threadIdx.x;
    const int total_w = LAYERS * WPL;
    if (idx < total_w) {
        int l = idx / WPL;
        int r = idx - l * WPL;
        int j    = r & 7;
        int lane = (r >> 3) & 63;
        int kt   = (r >> 9) & 15;
        int tile = r >> 13;
        int n = tile * 16 + (lane & 15);
        int k = kt * 32 + (lane >> 4) * 8 + j;
        float v;
        if (l == 0) {
            v = (k < 256) ? k0[(size_t)k * 768 + n] : rk0[(size_t)(k - 256) * 768 + n];
        } else {
            const float* kk = kern  + (size_t)(l - 1) * 256 * 768;
            const float* rk = rkern + (size_t)(l - 1) * 256 * 768;
            v = (k < 256) ? kk[(size_t)k * 768 + n] : rk[(size_t)(k - 256) * 768 + n];
        }
        Wp[idx] = (_Float16)v;
    } else {
        int ib = idx - total_w;
        if (ib < LAYERS * 1024) {
            int l = ib >> 10;
            int i = ib & 1023;
            const float* bs = (l == 0) ? b0 : (bias + (size_t)(l - 1) * 2 * 768);
            float v;
            if (i < 512)      v = bs[i] + bs[768 + i];
            else if (i < 768) v = bs[512 + (i - 512)];
            else              v = bs[768 + 512 + (i - 768)];
            Bp[l * 1024 + i] = v;
        }
    }
}

// ---------------------------------------------------------------------------
// Persistent GRU kernel: 384 threads = 6 waves; wave w computes one 16-col
// tile: w0,w1=z  w2,w3=r  w4,w5=h (split accumulators k<256 / k>=256).
// ---------------------------------------------------------------------------
__launch_bounds__(384, 1)
__global__ void gru_kernel(const float* __restrict__ x,
                           const _Float16* __restrict__ Wp,
                           const float* __restrict__ Bp,
                           ull* __restrict__ hbuf,
                           unsigned int* __restrict__ flags,
                           float* __restrict__ out)
{
    __shared__ _Float16 Af[2][16 * 512];   // fragment-ordered A, 16 KB each
    __shared__ float    Sc[8][16][17];     // 8.7 KB

    const int tid  = threadIdx.x;
    const int lane = tid & 63;
    const int w    = tid >> 6;
    const int lo16 = lane & 15;
    const int q    = lane >> 4;

    const int s = blockIdx.x & 7;          // unit slice
    const int c = (blockIdx.x >> 3) & 7;   // batch chunk
    const int l = blockIdx.x >> 6;         // layer
    const int b0row = c * 16;

    // ---- this wave's weight tile -> registers (once) ----
    const int tile = (w >> 1) * 16 + 2 * s + (w & 1);
    half8 bfrag[16];
    {
        const _Float16* wb = Wp + (size_t)l * WPL + (size_t)tile * TILE_STRIDE;
#pragma unroll
        for (int kt = 0; kt < 16; ++kt)
            bfrag[kt] = *(const half8*)(wb + ((size_t)kt * 64 + lane) * 8);
    }

    // ---- per-gate-thread mapping (tid<256: row grow, units gup,gup+1) ----
    const int grow = tid >> 4;
    const int g16  = tid & 15;
    const int gup  = g16 * 2;
    // fragment-store offsets for this thread's 16 k-elems (2 half8 groups)
    const int ktx  = g16 >> 1;
    const int qq   = (g16 & 1) * 2;
    const int xoff0 = ((ktx * 64) + qq * 16 + grow) * 8;
    const int xoff1 = ((ktx * 64) + (qq + 1) * 16 + grow) * 8;
    const int hoff0 = (((8 + ktx) * 64) + qq * 16 + grow) * 8;
    const int hoff1 = (((8 + ktx) * 64) + (qq + 1) * 16 + grow) * 8;

    float bz[2] = {0,0}, br[2] = {0,0}, bi[2] = {0,0}, bh[2] = {0,0};
    float hprev[2] = {0.f, 0.f};
    if (tid < 256) {
        const float* bp = Bp + l * 1024;
        int ug = s * 32 + gup;
        bz[0] = bp[ug];       bz[1] = bp[ug + 1];
        br[0] = bp[256 + ug]; br[1] = bp[256 + ug + 1];
        bi[0] = bp[512 + ug]; bi[1] = bp[512 + ug + 1];
        bh[0] = bp[768 + ug]; bh[1] = bp[768 + ug + 1];
    }

    unsigned int* fl_own_g = flags + (l * NCH + c) * 16;
    unsigned int* fl_dn_g  = flags + ((l < 3 ? l + 1 : 0) * NCH + c) * 16;
    unsigned int* my_flag  = fl_own_g + s;

    ull*       hb_own = hbuf + (size_t)(l * NCH + c) * GRP_ULL;
    const ull* hb_up  = hbuf + (size_t)((l > 0 ? l - 1 : 0) * NCH + c) * GRP_ULL;

    auto wait_group = [&](const unsigned int* base, unsigned need) {
        for (;;) {
            unsigned v = 0xFFFFFFFFu;
            if (lane < 8)
                v = __hip_atomic_load(base + lane, __ATOMIC_RELAXED, SCOPE);
            if (__all((int)(v >= need))) return;
            __builtin_amdgcn_s_sleep(1);
        }
    };

    auto stage_x = [&](int t, _Float16* An) {   // stage x(t) into An (tid<256)
        if (l == 0) {
            const float* sp = x + ((size_t)(b0row + grow) * TSTEPS + t) * 256 + gup * 8;
            f32x4 a0 = *(const f32x4*)sp,      a1 = *(const f32x4*)(sp + 4);
            f32x4 a2 = *(const f32x4*)(sp + 8), a3 = *(const f32x4*)(sp + 12);
            half8 h0, h1;
            h0[0]=(_Float16)a0[0]; h0[1]=(_Float16)a0[1]; h0[2]=(_Float16)a0[2]; h0[3]=(_Float16)a0[3];
            h0[4]=(_Float16)a1[0]; h0[5]=(_Float16)a1[1]; h0[6]=(_Float16)a1[2]; h0[7]=(_Float16)a1[3];
            h1[0]=(_Float16)a2[0]; h1[1]=(_Float16)a2[1]; h1[2]=(_Float16)a2[2]; h1[3]=(_Float16)a2[3];
            h1[4]=(_Float16)a3[0]; h1[5]=(_Float16)a3[1]; h1[6]=(_Float16)a3[2]; h1[7]=(_Float16)a3[3];
            *(half8*)(An + xoff0) = h0;
            *(half8*)(An + xoff1) = h1;
        } else {
            const ull* spx = hb_up + (size_t)(t & (RING - 1)) * SLOT_ULL + grow * 128 + g16 * 8;
            const unsigned tg = (unsigned)(t + 1);
            ull vx[8];
#pragma unroll
            for (int j = 0; j < 8; ++j)
                vx[j] = __hip_atomic_load(spx + j, __ATOMIC_RELAXED, SCOPE);
            for (;;) {
                bool ok = true;
#pragma unroll
                for (int j = 0; j < 8; ++j)
                    if ((unsigned)(vx[j] >> 32) != tg) {
                        vx[j] = __hip_atomic_load(spx + j, __ATOMIC_RELAXED, SCOPE);
                        ok = false;
                    }
                if (ok) break;
                __builtin_amdgcn_s_sleep(1);
            }
            uint4v w0, w1;
            w0[0]=(unsigned)vx[0]; w0[1]=(unsigned)vx[1]; w0[2]=(unsigned)vx[2]; w0[3]=(unsigned)vx[3];
            w1[0]=(unsigned)vx[4]; w1[1]=(unsigned)vx[5]; w1[2]=(unsigned)vx[6]; w1[3]=(unsigned)vx[7];
            *(uint4v*)(An + xoff0) = w0;
            *(uint4v*)(An + xoff1) = w1;
        }
    };

    // ---- prologue: x(0) + zero h into Af[0] ----
    if (tid < 256) {
        stage_x(0, Af[0]);
        uint4v z = {0u, 0u, 0u, 0u};
        *(uint4v*)(Af[0] + hoff0) = z;
        *(uint4v*)(Af[0] + hoff1) = z;
    }

    ull vh[8];   // prefetched own-h tagged words

    for (int t = 0; t < TSTEPS; ++t) {
        _Float16* A  = Af[t & 1];
        _Float16* An = Af[(t + 1) & 1];

        // ---- stage 1: validate prefetched own-h(t-1), stage into A ----
        if (t > 0 && tid < 256) {
            const ull* sph = hb_own + (size_t)((t - 1) & (RING - 1)) * SLOT_ULL + grow * 128 + g16 * 8;
            const unsigned tg = (unsigned)t;
            for (;;) {
                bool ok = true;
#pragma unroll
                for (int j = 0; j < 8; ++j)
                    if ((unsigned)(vh[j] >> 32) != tg) {
                        vh[j] = __hip_atomic_load(sph + j, __ATOMIC_RELAXED, SCOPE);
                        ok = false;
                    }
                if (ok) break;
            }
            uint4v w0, w1;
            w0[0]=(unsigned)vh[0]; w0[1]=(unsigned)vh[1]; w0[2]=(unsigned)vh[2]; w0[3]=(unsigned)vh[3];
            w1[0]=(unsigned)vh[4]; w1[1]=(unsigned)vh[5]; w1[2]=(unsigned)vh[6]; w1[3]=(unsigned)vh[7];
            *(uint4v*)(A + hoff0) = w0;
            *(uint4v*)(A + hoff1) = w1;
        }
        __syncthreads();   // B1: A complete

        // ---- stage 2: MFMA, a-frag = wave-contiguous ds_read_b128 ----
        f32x4 acc0 = {0,0,0,0}, acc1 = {0,0,0,0};
#pragma unroll
        for (int kt = 0; kt < 16; ++kt) {
            half8 a = *(const half8*)(A + ((kt * 64) + lane) * 8);
            if (w < 4 || kt < 8)
                acc0 = __builtin_amdgcn_mfma_f32_16x16x32_f16(a, bfrag[kt], acc0, 0, 0, 0);
            else
                acc1 = __builtin_amdgcn_mfma_f32_16x16x32_f16(a, bfrag[kt], acc1, 0, 0, 0);
        }
#pragma unroll
        for (int r = 0; r < 4; ++r) Sc[w][q * 4 + r][lo16] = acc0[r];
        if (w >= 4) {
#pragma unroll
            for (int r = 0; r < 4; ++r) Sc[w + 2][q * 4 + r][lo16] = acc1[r];
        }
        __syncthreads();   // B2: Sc complete

        // ---- ring backpressure before overwriting slot t ----
        if (l < 3 && t >= RING) wait_group(fl_dn_g, (unsigned)(t - RING + 1));

        // ---- stage 5: gates; publish tagged h(t) immediately ----
        if (tid < 256) {
            float hn[2];
#pragma unroll
            for (int j = 0; j < 2; ++j) {
                int u   = gup + j;
                int ut  = u >> 4;
                int col = u & 15;
                float zp = Sc[ut][grow][col]     + bz[j];
                float rp = Sc[2 + ut][grow][col] + br[j];
                float ip = Sc[4 + ut][grow][col] + bi[j];
                float hp = Sc[6 + ut][grow][col] + bh[j];
                float z  = 1.f / (1.f + __expf(-zp));
                float rr = 1.f / (1.f + __expf(-rp));
                float pre = ip + rr * hp;
                float e  = __expf(2.f * pre);
                float th = 1.f - 2.f / (e + 1.f);
                hn[j] = z * hprev[j] + (1.f - z) * th;
                hprev[j] = hn[j];
            }
            union { _Float16 h[2]; unsigned u32; } pk;
            pk.h[0] = (_Float16)hn[0];
            pk.h[1] = (_Float16)hn[1];
            ull word = ((ull)(unsigned)(t + 1) << 32) | (ull)pk.u32;
            __hip_atomic_store(hb_own + (size_t)(t & (RING - 1)) * SLOT_ULL + grow * 128 + s * 16 + g16,
                               word, __ATOMIC_RELAXED, SCOPE);
            if (l == 3 && t == TSTEPS - 1) {
                float* op = out + (size_t)(b0row + grow) * 256 + s * 32 + gup;
                op[0] = hn[0];
                op[1] = hn[1];
            }
        }

        // ---- stage 6: off-critical-path — stage x(t+1); prefetch own-h ----
        if (t + 1 < TSTEPS && tid < 256) {
            stage_x(t + 1, An);
            const ull* sph = hb_own + (size_t)(t & (RING - 1)) * SLOT_ULL + grow * 128 + g16 * 8;
#pragma unroll
            for (int j = 0; j < 8; ++j)
                vh[j] = __hip_atomic_load(sph + j, __ATOMIC_RELAXED, SCOPE);
        }
        __syncthreads();   // B3: step t fully consumed

        if (tid == 0)
            __hip_atomic_store(my_flag, (unsigned)(t + 1), __ATOMIC_RELAXED, SCOPE);
    }
}

extern "C" void kernel_launch(void* const* d_in, const int* in_sizes, int n_in,
                              void* d_out, int out_size, void* d_ws, size_t ws_size,
                              hipStream_t stream)
{
    const float* x     = (const float*)d_in[0];
    const float* k0    = (const float*)d_in[1];
    const float* rk0   = (const float*)d_in[2];
    const float* b0    = (const float*)d_in[3];
    const float* kern  = (const float*)d_in[4];
    const float* rkern = (const float*)d_in[5];
    const float* bias  = (const float*)d_in[6];
    float* out = (float*)d_out;

    char* ws = (char*)d_ws;
    _Float16*     Wp    = (_Float16*)(ws + WP_OFF);
    float*        Bp    = (float*)(ws + BP_OFF);
    unsigned int* flags = (unsigned int*)(ws + FLAG_OFF);
    ull*          hbuf  = (ull*)(ws + HBUF_OFF);

    hipMemsetAsync(flags, 0, FLAG_BYTES, stream);

    const int total = LAYERS * WPL + LAYERS * 1024;
    repack_kernel<<<(total + 255) / 256, 256, 0, stream>>>(k0, rk0, b0, kern, rkern, bias, Wp, Bp);

    gru_kernel<<<LAYERS * NCH * 8, 384, 0, stream>>>(x, Wp, Bp, hbuf, flags, out);
}